// Round 1
// baseline (1309.911 us; speedup 1.0000x reference)
//
#include <hip/hip_runtime.h>
#include <math.h>

// Problem constants (fixed by setup_inputs)
#define NB 16      // batch
#define NO 128     // output channels
#define ND 64      // manifold dim
#define NN 30      // grid side
#define NM 27000   // NN^3

// ---------------------------------------------------------------------------
// Pointwise gyroplane signed-distance given precomputed dots.
// Matches reference normdist2plane exactly (C=1, SQRT_C=1, MIN_NORM=1e-15).
// ---------------------------------------------------------------------------
__device__ __forceinline__ float gyro_dist(float x2, float dp, float da,
                                           float p2, float pa, float an) {
    float beta  = 1.0f - p2;
    float alpha = 1.0f - 2.0f * dp + x2;
    float den   = fmaxf(1.0f - 2.0f * dp + p2 * x2, 1e-15f);
    float sc    = (-alpha * pa + beta * da) / den;
    float dn2   = fmaxf((alpha * alpha * p2 - 2.0f * alpha * beta * dp + beta * beta * x2)
                        / (den * den), 1e-15f);
    float num   = 2.0f * sc;
    float denom = fmaxf((1.0f - dn2) * an, 1e-15f);
    return asinhf(num / denom);
}

// ---------------------------------------------------------------------------
// Per-o params: p = proj(expmap0(w*b)), a = w*max(1-|p|^2,eps), plus scalars.
// Threads 0..31 each handle one o of a 32-wide chunk; p_s/a_s stored [d][o]
// (stride 32) so compute-phase reads are broadcast / conflict-free.
// p_s is used as scratch (u -> g -> p) during the computation.
// ---------------------------------------------------------------------------
__device__ void compute_params_chunk(const float* __restrict__ w,
                                     const float* __restrict__ bias,
                                     int oc0,
                                     float* p_s, float* a_s,
                                     float* p2_s, float* pa_s, float* an_s,
                                     int tid) {
    if (tid < 32) {
        int o = oc0 + tid;
        const float* wr = w + o * ND;
        float bb = bias[o];
        float un2 = 0.0f;
        for (int d = 0; d < ND; ++d) {
            float u = wr[d] * bb;
            p_s[d * 32 + tid] = u;
            un2 += u * u;
        }
        float un  = fmaxf(sqrtf(un2), 1e-15f);
        float t1  = tanhf(fminf(un, 15.0f));
        float sc1 = t1 / un;
        float gn2 = 0.0f;
        for (int d = 0; d < ND; ++d) {
            float g = p_s[d * 32 + tid] * sc1;
            p_s[d * 32 + tid] = g;
            gn2 += g * g;
        }
        float gn  = fmaxf(sqrtf(gn2), 1e-15f);
        float sc2 = (gn > 0.996f) ? (0.996f / gn) : 1.0f;
        float p2  = 0.0f;
        for (int d = 0; d < ND; ++d) {
            float p = p_s[d * 32 + tid] * sc2;
            p_s[d * 32 + tid] = p;
            p2 += p * p;
        }
        float betaC = fmaxf(1.0f - p2, 1e-15f);
        float pa = 0.0f, a2 = 0.0f;
        for (int d = 0; d < ND; ++d) {
            float a = wr[d] * betaC;
            a_s[d * 32 + tid] = a;
            pa += p_s[d * 32 + tid] * a;
            a2 += a * a;
        }
        p2_s[tid] = p2;
        pa_s[tid] = pa;
        an_s[tid] = fmaxf(sqrtf(a2), 1e-15f);
    }
}

// dist at the origin (zero-padded points): x2=0, dots=0.
__device__ float compute_dist0(const float* __restrict__ w,
                               const float* __restrict__ bias, int o) {
    const float* wr = w + o * ND;
    float bb = bias[o];
    float un2 = 0.0f;
    for (int d = 0; d < ND; ++d) { float u = wr[d] * bb; un2 += u * u; }
    float un  = fmaxf(sqrtf(un2), 1e-15f);
    float t1  = tanhf(fminf(un, 15.0f));
    float sc1 = t1 / un;
    float gn2 = 0.0f;
    for (int d = 0; d < ND; ++d) { float g = wr[d] * bb * sc1; gn2 += g * g; }
    float gn  = fmaxf(sqrtf(gn2), 1e-15f);
    float sc2 = (gn > 0.996f) ? (0.996f / gn) : 1.0f;
    float p2 = 0.0f;
    for (int d = 0; d < ND; ++d) { float p = wr[d] * bb * sc1 * sc2; p2 += p * p; }
    float betaC = fmaxf(1.0f - p2, 1e-15f);
    float pa = 0.0f, a2 = 0.0f;
    for (int d = 0; d < ND; ++d) {
        float p = wr[d] * bb * sc1 * sc2;
        float a = wr[d] * betaC;
        pa += p * a; a2 += a * a;
    }
    float an  = fmaxf(sqrtf(a2), 1e-15f);
    float dn2 = fmaxf(p2, 1e-15f);
    float denom = fmaxf((1.0f - dn2) * an, 1e-15f);
    return asinhf((-2.0f * pa) / denom);
}

// ---------------------------------------------------------------------------
// Kernel 1: dist[b][o][m] for all real grid points, written into d_out.
// Block: (m-chunk of 128) x (o-chunk of 32) x b.  256 threads.
// Thread: 2 m x 8 o accumulators; x tile in LDS (stride 65), p/a broadcast.
// ---------------------------------------------------------------------------
__global__ __launch_bounds__(256) void gyro_dist_kernel(
    const float* __restrict__ x, const float* __restrict__ w,
    const float* __restrict__ bias, float* __restrict__ dist) {
    __shared__ __align__(16) float p_s[ND * 32];
    __shared__ __align__(16) float a_s[ND * 32];
    __shared__ float p2_s[32], pa_s[32], an_s[32];
    __shared__ float x_s[128 * 65];

    const int tid = threadIdx.x;
    const int mc = blockIdx.x, oc = blockIdx.y, b = blockIdx.z;
    const int oc0 = oc * 32, m0 = mc * 128;

    compute_params_chunk(w, bias, oc0, p_s, a_s, p2_s, pa_s, an_s, tid);

    for (int v = tid; v < 128 * 64; v += 256) {
        int mi = v >> 6, d = v & 63;
        int m = m0 + mi;
        x_s[mi * 65 + d] = (m < NM) ? x[((size_t)m * NB + b) * ND + d] : 0.0f;
    }
    __syncthreads();

    const int ml = tid & 63;
    const int og = tid >> 6;   // 0..3
    const int ob = og * 8;

    float dp[2][8], da[2][8], xx2[2];
    xx2[0] = 0.0f; xx2[1] = 0.0f;
#pragma unroll
    for (int mm = 0; mm < 2; ++mm)
#pragma unroll
        for (int j = 0; j < 8; ++j) { dp[mm][j] = 0.0f; da[mm][j] = 0.0f; }

    for (int d = 0; d < ND; ++d) {
        float xv0 = x_s[ml * 65 + d];
        float xv1 = x_s[(ml + 64) * 65 + d];
        xx2[0] += xv0 * xv0;
        xx2[1] += xv1 * xv1;
        float pv[8], av[8];
        *(float4*)&pv[0] = *(const float4*)&p_s[d * 32 + ob];
        *(float4*)&pv[4] = *(const float4*)&p_s[d * 32 + ob + 4];
        *(float4*)&av[0] = *(const float4*)&a_s[d * 32 + ob];
        *(float4*)&av[4] = *(const float4*)&a_s[d * 32 + ob + 4];
#pragma unroll
        for (int j = 0; j < 8; ++j) {
            dp[0][j] += xv0 * pv[j];
            da[0][j] += xv0 * av[j];
            dp[1][j] += xv1 * pv[j];
            da[1][j] += xv1 * av[j];
        }
    }

#pragma unroll
    for (int mm = 0; mm < 2; ++mm) {
        int m = m0 + ml + mm * 64;
        if (m < NM) {
#pragma unroll
            for (int j = 0; j < 8; ++j) {
                int ol = ob + j;
                float dv = gyro_dist(xx2[mm], dp[mm][j], da[mm][j],
                                     p2_s[ol], pa_s[ol], an_s[ol]);
                dist[((size_t)(b * NO + oc0 + ol)) * NM + m] = dv;
            }
        }
    }
}

// ---------------------------------------------------------------------------
// Kernel 2: separable box sum along k then j, in-place on d_out.
// Block owns one (b,o,i) plane of 30x30 -> loads it fully to LDS first, so
// in-place is safe. Zero-padded neighbors contribute dist0 (k-pass) and
// 3*dist0 (j-pass, an entire padded row's k-sum).
// ---------------------------------------------------------------------------
__global__ __launch_bounds__(256) void gyro_pass_jk(
    float* __restrict__ dist, const float* __restrict__ w,
    const float* __restrict__ bias) {
    __shared__ float v[NN * NN];
    __shared__ float s1[NN * NN];
    __shared__ float d0sh;
    const int i = blockIdx.x, o = blockIdx.y, b = blockIdx.z;
    const int tid = threadIdx.x;
    float* plane = dist + ((size_t)(b * NO + o)) * NM + i * (NN * NN);

    for (int t = tid; t < NN * NN; t += 256) v[t] = plane[t];
    if (tid == 0) d0sh = compute_dist0(w, bias, o);
    __syncthreads();
    const float d0 = d0sh;

    for (int t = tid; t < NN * NN; t += 256) {
        int k = t % NN;
        s1[t] = v[t] + (k == 0 ? d0 : v[t - 1]) + (k == NN - 1 ? d0 : v[t + 1]);
    }
    __syncthreads();
    const float T = 3.0f * d0;
    for (int t = tid; t < NN * NN; t += 256) {
        int j = t / NN;
        plane[t] = s1[t] + (j == 0 ? T : s1[t - NN]) + (j == NN - 1 ? T : s1[t + NN]);
    }
}

// ---------------------------------------------------------------------------
// Kernel 3: separable box sum along i, in-place. Block owns one (b,o,j)
// stripe of 30(i) x 30(k). Padded i-planes contribute 9*dist0 after the
// k+j passes.
// ---------------------------------------------------------------------------
__global__ __launch_bounds__(256) void gyro_pass_i(
    float* __restrict__ dist, const float* __restrict__ w,
    const float* __restrict__ bias) {
    __shared__ float v[NN * NN];
    __shared__ float d0sh;
    const int j = blockIdx.x, o = blockIdx.y, b = blockIdx.z;
    const int tid = threadIdx.x;
    float* base = dist + ((size_t)(b * NO + o)) * NM + j * NN;

    for (int t = tid; t < NN * NN; t += 256) {
        int i = t / NN, k = t % NN;
        v[t] = base[(size_t)i * (NN * NN) + k];
    }
    if (tid == 0) d0sh = compute_dist0(w, bias, o);
    __syncthreads();
    const float T = 9.0f * d0sh;
    for (int t = tid; t < NN * NN; t += 256) {
        int i = t / NN, k = t % NN;
        float sum = v[t] + (i == 0 ? T : v[t - NN]) + (i == NN - 1 ? T : v[t + NN]);
        base[(size_t)i * (NN * NN) + k] = sum;
    }
}

extern "C" void kernel_launch(void* const* d_in, const int* in_sizes, int n_in,
                              void* d_out, int out_size, void* d_ws, size_t ws_size,
                              hipStream_t stream) {
    const float* x    = (const float*)d_in[0];   // (M, B, D)
    const float* w    = (const float*)d_in[1];   // (O, D)
    const float* bias = (const float*)d_in[2];   // (O, 1)
    float* out = (float*)d_out;                  // (B, O, N, N, N)

    // dist -> d_out, then separable in-place 3x3x3 box sum
    dim3 gD((NM + 127) / 128, NO / 32, NB);      // (211, 4, 16)
    gyro_dist_kernel<<<gD, 256, 0, stream>>>(x, w, bias, out);

    dim3 gP(NN, NO, NB);                          // (30, 128, 16)
    gyro_pass_jk<<<gP, 256, 0, stream>>>(out, w, bias);
    gyro_pass_i<<<gP, 256, 0, stream>>>(out, w, bias);
}

// Round 3
// 649.411 us; speedup vs baseline: 2.0171x; 2.0171x over previous
//
#include <hip/hip_runtime.h>
#include <math.h>

#define NB 16      // batch
#define NO 128     // output channels
#define ND 64      // manifold dim
#define NN 30      // grid side
#define NM 27000   // NN^3

typedef _Float16 half8 __attribute__((ext_vector_type(8)));
typedef float    f32x4 __attribute__((ext_vector_type(4)));

// ---------------------------------------------------------------------------
// fast asinh: log(t + sqrt(t^2+1)), HW log/sqrt. abs tolerance ~1.0,
// rel error of v_log/v_rcp (~1e-7) is irrelevant.
// ---------------------------------------------------------------------------
__device__ __forceinline__ float asinh_fast(float t) {
    return __logf(t + __builtin_amdgcn_sqrtf(t * t + 1.0f));
}

__device__ __forceinline__ float gyro_dist(float x2, float dp, float da,
                                           float p2, float pa, float an) {
    float beta  = 1.0f - p2;
    float alpha = 1.0f - 2.0f * dp + x2;
    float den   = fmaxf(1.0f - 2.0f * dp + p2 * x2, 1e-15f);
    float rden  = __builtin_amdgcn_rcpf(den);
    float sc    = (beta * da - alpha * pa) * rden;
    float dn2   = fmaxf((alpha * alpha * p2 - 2.0f * alpha * beta * dp +
                         beta * beta * x2) * (rden * rden), 1e-15f);
    float denom = fmaxf((1.0f - dn2) * an, 1e-15f);
    float t     = 2.0f * sc * __builtin_amdgcn_rcpf(denom);
    return asinh_fast(t);
}

// ---------------------------------------------------------------------------
// Param algebra collapsed to scalars of S = sum_d w[o][d]^2 (exact rewrite of
// the reference expmap0/project/transp0 chain):
//   un = |b|*sqrt(S); t1 = tanh(min(un,15)); sc1 = t1/un; gn = t1
//   sc2 = gn>0.996 ? 0.996/gn : 1;  fp = b*sc1*sc2
//   p[d] = w[d]*fp;  p2 = fp^2*S;  betaC = max(1-p2,eps)
//   a[d] = w[d]*betaC;  pa = fp*betaC*S;  an = betaC*sqrt(S)
// ---------------------------------------------------------------------------
__device__ __forceinline__ void param_scalars(float S, float bb,
                                              float* fp_o, float* p2_o,
                                              float* betaC_o, float* pa_o,
                                              float* an_o) {
    float sq  = sqrtf(S);
    float un  = fmaxf(fabsf(bb) * sq, 1e-15f);
    float t1  = tanhf(fminf(un, 15.0f));
    float sc1 = t1 / un;
    float gn  = fmaxf(t1, 1e-15f);
    float sc2 = (gn > 0.996f) ? (0.996f / gn) : 1.0f;
    float fp  = bb * sc1 * sc2;
    float p2  = fp * fp * S;
    float betaC = fmaxf(1.0f - p2, 1e-15f);
    *fp_o = fp; *p2_o = p2; *betaC_o = betaC;
    *pa_o = fp * betaC * S;
    *an_o = fmaxf(betaC * sq, 1e-15f);
}

// dist at origin, computed cooperatively by first wave; result in *out_lds
// (valid after __syncthreads()).
__device__ __forceinline__ void dist0_wave(const float* __restrict__ w,
                                           const float* __restrict__ bias,
                                           int o, int tid, float* out_lds) {
    if (tid < 64) {
        float v = w[o * ND + tid];
        float s = v * v;
#pragma unroll
        for (int off = 32; off > 0; off >>= 1) s += __shfl_xor(s, off, 64);
        if (tid == 0) {
            float fp, p2, betaC, pa, an;
            param_scalars(s, bias[o], &fp, &p2, &betaC, &pa, &an);
            float dn2   = fmaxf(p2, 1e-15f);
            float denom = fmaxf((1.0f - dn2) * an, 1e-15f);
            *out_lds = asinh_fast(-2.0f * pa * __builtin_amdgcn_rcpf(denom));
        }
    }
}

// ---------------------------------------------------------------------------
// Kernel 1: dist[b][o][m] via MFMA f16 into `dist` (workspace or d_out).
// Block: 256 threads (4 waves), m-tile = 64, all 128 o.
//   A-frag: A[m=lane&15][k=quad*8+j]   (8 f16 / lane)
//   B-frag: B[k=quad*8+j][o=lane&15]
//   D:      row(m)=quad*4+reg, col(o)=lane&15  -> 4 consecutive m per lane
// ---------------------------------------------------------------------------
__global__ __launch_bounds__(256) void gyro_dist_mfma(
    const float* __restrict__ x, const float* __restrict__ w,
    const float* __restrict__ bias, float* __restrict__ dist) {
    __shared__ __align__(16) half8 xf[8 * 64];     // 8 KB : 4 mt x 2 h
    __shared__ __align__(16) half8 pf[16 * 64];    // 16 KB: 8 otile x 2 h
    __shared__ __align__(16) half8 af[16 * 64];    // 16 KB
    __shared__ float p2_s[NO], pa_s[NO], an_s[NO];
    __shared__ float x2p[64 * 8];
    __shared__ __align__(16) float x2_s[64];

    const int tid = threadIdx.x;
    const int m0  = blockIdx.x * 64;
    const int b   = blockIdx.y;

    // ---- per-o params -> f16 fragments (threads 0..127, one o each) ----
    if (tid < NO) {
        int o = tid;
        const float* wr = w + o * ND;
        float bb = bias[o];
        float S = 0.0f;
        for (int d = 0; d < ND; ++d) S += wr[d] * wr[d];
        float fp, p2, betaC, pa, an;
        param_scalars(S, bb, &fp, &p2, &betaC, &pa, &an);
        p2_s[o] = p2; pa_s[o] = pa; an_s[o] = an;
        int ot = o >> 4, j = o & 15;
#pragma unroll
        for (int h = 0; h < 2; ++h)
#pragma unroll
            for (int q = 0; q < 4; ++q) {
                int d0 = h * 32 + q * 8;
                half8 hp, ha;
#pragma unroll
                for (int jj = 0; jj < 8; ++jj) {
                    float wv = wr[d0 + jj];
                    hp[jj] = (_Float16)(wv * fp);
                    ha[jj] = (_Float16)(wv * betaC);
                }
                pf[(ot * 2 + h) * 64 + j + 16 * q] = hp;
                af[(ot * 2 + h) * 64 + j + 16 * q] = ha;
            }
    }

    // ---- stage x tile: 512 fragment slots of 8 f32 -> f16, + x2 partials ----
    for (int s = tid; s < 512; s += 256) {
        int f = s >> 6, lane = s & 63;
        int mt = f >> 1, h = f & 1;
        int mloc = mt * 16 + (lane & 15);
        int quad = lane >> 4;
        int k0 = h * 32 + quad * 8;
        int gm = m0 + mloc;
        half8 hv;
        float part = 0.0f;
        if (gm < NM) {
            const float4* src = (const float4*)(x + ((size_t)gm * NB + b) * ND + k0);
            float4 v0 = src[0], v1 = src[1];
            float vv[8] = {v0.x, v0.y, v0.z, v0.w, v1.x, v1.y, v1.z, v1.w};
#pragma unroll
            for (int jj = 0; jj < 8; ++jj) {
                hv[jj] = (_Float16)vv[jj];
                part += vv[jj] * vv[jj];
            }
        } else {
#pragma unroll
            for (int jj = 0; jj < 8; ++jj) hv[jj] = (_Float16)0.0f;
        }
        xf[f * 64 + lane] = hv;
        x2p[mloc * 8 + h * 4 + quad] = part;
    }
    __syncthreads();
    if (tid < 64) {
        float s = 0.0f;
#pragma unroll
        for (int r = 0; r < 8; ++r) s += x2p[tid * 8 + r];
        x2_s[tid] = s;
    }
    __syncthreads();

    // ---- MFMA main: per wave, 4 m-tiles x 2 o-tiles x {p,a} ----
    const int lane = tid & 63;
    const int wid  = tid >> 6;      // o-range = wid*32 .. +32

    f32x4 accp[4][2], acca[4][2];
#pragma unroll
    for (int mt = 0; mt < 4; ++mt)
#pragma unroll
        for (int ot = 0; ot < 2; ++ot) {
            accp[mt][ot] = (f32x4)0.0f;
            acca[mt][ot] = (f32x4)0.0f;
        }

#pragma unroll
    for (int h = 0; h < 2; ++h) {
        half8 afr[4], bp[2], ba[2];
#pragma unroll
        for (int mt = 0; mt < 4; ++mt) afr[mt] = xf[(mt * 2 + h) * 64 + lane];
#pragma unroll
        for (int ot = 0; ot < 2; ++ot) {
            bp[ot] = pf[((wid * 2 + ot) * 2 + h) * 64 + lane];
            ba[ot] = af[((wid * 2 + ot) * 2 + h) * 64 + lane];
        }
#pragma unroll
        for (int mt = 0; mt < 4; ++mt)
#pragma unroll
            for (int ot = 0; ot < 2; ++ot) {
                accp[mt][ot] = __builtin_amdgcn_mfma_f32_16x16x32_f16(
                    afr[mt], bp[ot], accp[mt][ot], 0, 0, 0);
                acca[mt][ot] = __builtin_amdgcn_mfma_f32_16x16x32_f16(
                    afr[mt], ba[ot], acca[mt][ot], 0, 0, 0);
            }
    }

    // ---- epilogue: 4 consecutive m per lane -> dwordx4 store ----
    const int lo = lane & 15, quad = lane >> 4;
#pragma unroll
    for (int mt = 0; mt < 4; ++mt) {
#pragma unroll
        for (int ot = 0; ot < 2; ++ot) {
            int o  = wid * 32 + ot * 16 + lo;
            int mb = mt * 16 + quad * 4;
            int gm = m0 + mb;
            if (gm < NM) {
                float4 x2v = *(const float4*)&x2_s[mb];
                float P2 = p2_s[o], PA = pa_s[o], AN = an_s[o];
                float4 dv;
                dv.x = gyro_dist(x2v.x, accp[mt][ot][0], acca[mt][ot][0], P2, PA, AN);
                dv.y = gyro_dist(x2v.y, accp[mt][ot][1], acca[mt][ot][1], P2, PA, AN);
                dv.z = gyro_dist(x2v.z, accp[mt][ot][2], acca[mt][ot][2], P2, PA, AN);
                dv.w = gyro_dist(x2v.w, accp[mt][ot][3], acca[mt][ot][3], P2, PA, AN);
                *(float4*)(dist + ((size_t)(b * NO + o)) * NM + gm) = dv;
            }
        }
    }
}

// ---------------------------------------------------------------------------
// Kernel 2 (workspace path): 3x3x3 box sum src -> dst in ONE kernel.
// src is read-only => no cross-block in-place race (the R2 bug).
// Block = (slab of 8 i-planes, o, b); loads planes i0-1..i0+8 (OOB -> d0),
// separable k-pass (vin->ktmp), j-pass (ktmp->vin), i-pass fused with store.
// ---------------------------------------------------------------------------
__global__ __launch_bounds__(256) void gyro_box3d(
    const float* __restrict__ src, float* __restrict__ dst,
    const float* __restrict__ w, const float* __restrict__ bias) {
    __shared__ __align__(16) float vin[10 * 900];   // 36 KB
    __shared__ __align__(16) float ktmp[10 * 900];  // 36 KB
    __shared__ float d0sh;

    const int tid = threadIdx.x;
    const int i0  = blockIdx.x * 8;
    const int o   = blockIdx.y;
    const int b   = blockIdx.z;

    dist0_wave(w, bias, o, tid, &d0sh);
    __syncthreads();
    const float d0 = d0sh;

    const float4* src4 = (const float4*)(src + ((size_t)(b * NO + o)) * NM);
    float4* dst4 = (float4*)(dst + ((size_t)(b * NO + o)) * NM);
    float4* vin4 = (float4*)vin;

    for (int idx = tid; idx < 10 * 225; idx += 256) {
        int sl = idx / 225, q = idx % 225;
        int ip = i0 - 1 + sl;
        float4 v;
        if (ip >= 0 && ip < NN) v = src4[ip * 225 + q];
        else { v.x = d0; v.y = d0; v.z = d0; v.w = d0; }
        vin4[sl * 225 + q] = v;
    }
    __syncthreads();

    for (int t = tid; t < 9000; t += 256) {
        int k = t % NN;
        ktmp[t] = vin[t] + (k == 0 ? d0 : vin[t - 1]) +
                  (k == NN - 1 ? d0 : vin[t + 1]);
    }
    __syncthreads();
    const float T3 = 3.0f * d0;
    for (int t = tid; t < 9000; t += 256) {
        int j = (t % 900) / NN;
        vin[t] = ktmp[t] + (j == 0 ? T3 : ktmp[t - NN]) +
                 (j == NN - 1 ? T3 : ktmp[t + NN]);
    }
    __syncthreads();
    const int nout = (i0 + 8 <= NN) ? 8 : (NN - i0);
    for (int idx = tid; idx < nout * 225; idx += 256) {
        int pl = idx / 225, q = idx % 225;
        float4 a = vin4[pl * 225 + q];
        float4 c = vin4[(pl + 1) * 225 + q];
        float4 e = vin4[(pl + 2) * 225 + q];
        float4 s;
        s.x = a.x + c.x + e.x; s.y = a.y + c.y + e.y;
        s.z = a.z + c.z + e.z; s.w = a.w + c.w + e.w;
        dst4[(i0 + pl) * 225 + q] = s;
    }
}

// ---------------------------------------------------------------------------
// Fallback path (no workspace): race-free in-place two-pass filter.
// Each block's read set == its write set (R1-verified structure).
// ---------------------------------------------------------------------------
__global__ __launch_bounds__(256) void gyro_pass_jk(
    float* __restrict__ dist, const float* __restrict__ w,
    const float* __restrict__ bias) {
    __shared__ float v[NN * NN];
    __shared__ float s1[NN * NN];
    __shared__ float d0sh;
    const int i = blockIdx.x, o = blockIdx.y, b = blockIdx.z;
    const int tid = threadIdx.x;
    float* plane = dist + ((size_t)(b * NO + o)) * NM + i * (NN * NN);

    dist0_wave(w, bias, o, tid, &d0sh);
    for (int t = tid; t < NN * NN; t += 256) v[t] = plane[t];
    __syncthreads();
    const float d0 = d0sh;

    for (int t = tid; t < NN * NN; t += 256) {
        int k = t % NN;
        s1[t] = v[t] + (k == 0 ? d0 : v[t - 1]) + (k == NN - 1 ? d0 : v[t + 1]);
    }
    __syncthreads();
    const float T = 3.0f * d0;
    for (int t = tid; t < NN * NN; t += 256) {
        int j = t / NN;
        plane[t] = s1[t] + (j == 0 ? T : s1[t - NN]) + (j == NN - 1 ? T : s1[t + NN]);
    }
}

__global__ __launch_bounds__(256) void gyro_pass_i(
    float* __restrict__ dist, const float* __restrict__ w,
    const float* __restrict__ bias) {
    __shared__ float v[NN * NN];
    __shared__ float d0sh;
    const int j = blockIdx.x, o = blockIdx.y, b = blockIdx.z;
    const int tid = threadIdx.x;
    float* base = dist + ((size_t)(b * NO + o)) * NM + j * NN;

    dist0_wave(w, bias, o, tid, &d0sh);
    for (int t = tid; t < NN * NN; t += 256) {
        int i = t / NN, k = t % NN;
        v[t] = base[(size_t)i * (NN * NN) + k];
    }
    __syncthreads();
    const float T = 9.0f * d0sh;
    for (int t = tid; t < NN * NN; t += 256) {
        int i = t / NN, k = t % NN;
        float sum = v[t] + (i == 0 ? T : v[t - NN]) + (i == NN - 1 ? T : v[t + NN]);
        base[(size_t)i * (NN * NN) + k] = sum;
    }
}

extern "C" void kernel_launch(void* const* d_in, const int* in_sizes, int n_in,
                              void* d_out, int out_size, void* d_ws, size_t ws_size,
                              hipStream_t stream) {
    const float* x    = (const float*)d_in[0];   // (M, B, D)
    const float* w    = (const float*)d_in[1];   // (O, D)
    const float* bias = (const float*)d_in[2];   // (O, 1)
    float* out = (float*)d_out;                  // (B, O, N, N, N)

    const size_t need = (size_t)NB * NO * NM * sizeof(float);  // 221 MB
    dim3 gD((NM + 63) / 64, NB);                 // (422, 16)

    if (ws_size >= need) {
        float* tmp = (float*)d_ws;
        gyro_dist_mfma<<<gD, 256, 0, stream>>>(x, w, bias, tmp);
        dim3 gB(4, NO, NB);                      // slabs x o x b = 8192
        gyro_box3d<<<gB, 256, 0, stream>>>(tmp, out, w, bias);
    } else {
        gyro_dist_mfma<<<gD, 256, 0, stream>>>(x, w, bias, out);
        dim3 gP(NN, NO, NB);                     // (30, 128, 16)
        gyro_pass_jk<<<gP, 256, 0, stream>>>(out, w, bias);
        gyro_pass_i<<<gP, 256, 0, stream>>>(out, w, bias);
    }
}

// Round 4
// 437.099 us; speedup vs baseline: 2.9968x; 1.4857x over previous
//
#include <hip/hip_runtime.h>
#include <math.h>

#define NB 16      // batch
#define NO 128     // output channels
#define ND 64      // manifold dim
#define NN 30      // grid side
#define NM 27000   // NN^3
#define PROW 32    // k-padded row length
#define PPLANE 960 // 30*PROW
#define PML 28800  // 30*PPLANE  (padded points per (b,o))

typedef _Float16 half8 __attribute__((ext_vector_type(8)));
typedef _Float16 half4 __attribute__((ext_vector_type(4)));
typedef float    f32x4 __attribute__((ext_vector_type(4)));

// ---------------------------------------------------------------------------
__device__ __forceinline__ float asinh_fast(float t) {
    return __logf(t + __builtin_amdgcn_sqrtf(t * t + 1.0f));
}

__device__ __forceinline__ float gyro_dist(float x2, float dp, float da,
                                           float p2, float pa, float an) {
    float beta  = 1.0f - p2;
    float alpha = 1.0f - 2.0f * dp + x2;
    float den   = fmaxf(1.0f - 2.0f * dp + p2 * x2, 1e-15f);
    float rden  = __builtin_amdgcn_rcpf(den);
    float sc    = (beta * da - alpha * pa) * rden;
    float dn2   = fmaxf((alpha * alpha * p2 - 2.0f * alpha * beta * dp +
                         beta * beta * x2) * (rden * rden), 1e-15f);
    float denom = fmaxf((1.0f - dn2) * an, 1e-15f);
    float t     = 2.0f * sc * __builtin_amdgcn_rcpf(denom);
    return asinh_fast(t);
}

// Param algebra collapsed to scalars of S = sum_d w[o][d]^2 (exact rewrite
// of the reference expmap0/project/transp0 chain).
__device__ __forceinline__ void param_scalars(float S, float bb,
                                              float* fp_o, float* p2_o,
                                              float* betaC_o, float* pa_o,
                                              float* an_o) {
    float sq  = sqrtf(S);
    float un  = fmaxf(fabsf(bb) * sq, 1e-15f);
    float t1  = tanhf(fminf(un, 15.0f));
    float sc1 = t1 / un;
    float gn  = fmaxf(t1, 1e-15f);
    float sc2 = (gn > 0.996f) ? (0.996f / gn) : 1.0f;
    float fp  = bb * sc1 * sc2;
    float p2  = fp * fp * S;
    float betaC = fmaxf(1.0f - p2, 1e-15f);
    *fp_o = fp; *p2_o = p2; *betaC_o = betaC;
    *pa_o = fp * betaC * S;
    *an_o = fmaxf(betaC * sq, 1e-15f);
}

// dist at origin; first wave computes, result valid after __syncthreads()
__device__ __forceinline__ void dist0_wave(const float* __restrict__ w,
                                           const float* __restrict__ bias,
                                           int o, int tid, float* out_lds) {
    if (tid < 64) {
        float v = w[o * ND + tid];
        float s = v * v;
#pragma unroll
        for (int off = 32; off > 0; off >>= 1) s += __shfl_xor(s, off, 64);
        if (tid == 0) {
            float fp, p2, betaC, pa, an;
            param_scalars(s, bias[o], &fp, &p2, &betaC, &pa, &an);
            float dn2   = fmaxf(p2, 1e-15f);
            float denom = fmaxf((1.0f - dn2) * an, 1e-15f);
            *out_lds = asinh_fast(-2.0f * pa * __builtin_amdgcn_rcpf(denom));
        }
    }
}

// ---------------------------------------------------------------------------
// Kernel 0: per-o params -> global (f16 B-fragments + f32 scalars).
// Fragment layout matches the dist kernel's per-lane read:
//   frag[(ot8*2+h)*64 + (o&15) + 16*q] holds B[k=h*32+q*8+jj][o]
// ---------------------------------------------------------------------------
__global__ __launch_bounds__(128) void gyro_params_k(
    const float* __restrict__ w, const float* __restrict__ bias,
    _Float16* __restrict__ pfg, _Float16* __restrict__ afg,
    float* __restrict__ p2g, float* __restrict__ pag,
    float* __restrict__ ang) {
    int o = threadIdx.x;            // 128 threads, one o each
    const float* wr = w + o * ND;
    float bb = bias[o];
    float S = 0.0f;
    for (int d = 0; d < ND; ++d) S += wr[d] * wr[d];
    float fp, p2, betaC, pa, an;
    param_scalars(S, bb, &fp, &p2, &betaC, &pa, &an);
    p2g[o] = p2; pag[o] = pa; ang[o] = an;

    half8* pf8 = (half8*)pfg;
    half8* af8 = (half8*)afg;
    int ot8 = o >> 4, j = o & 15;
#pragma unroll
    for (int h = 0; h < 2; ++h)
#pragma unroll
        for (int q = 0; q < 4; ++q) {
            int d0i = h * 32 + q * 8;
            half8 hp, ha;
#pragma unroll
            for (int jj = 0; jj < 8; ++jj) {
                float wv = wr[d0i + jj];
                hp[jj] = (_Float16)(wv * fp);
                ha[jj] = (_Float16)(wv * betaC);
            }
            pf8[(ot8 * 2 + h) * 64 + j + 16 * q] = hp;
            af8[(ot8 * 2 + h) * 64 + j + 16 * q] = ha;
        }
}

// ---------------------------------------------------------------------------
// Kernel 1: dist -> f16 k-padded tmp [b][o][row<900>][32].
// Grid (450, 16): 64 padded-m per block (450*64 == 28800 exactly).
// Pad cols (k=30,31) load x=0 -> dist = d0 (the box filter's edge value).
// B-fragments (p,a) in registers from gyro_params_k; LDS only for x-tile.
// ---------------------------------------------------------------------------
__global__ __launch_bounds__(256) void gyro_dist_mfma_h(
    const float* __restrict__ x,
    const _Float16* __restrict__ pfg, const _Float16* __restrict__ afg,
    const float* __restrict__ p2g, const float* __restrict__ pag,
    const float* __restrict__ ang,
    _Float16* __restrict__ tmp) {
    __shared__ __align__(16) half8 xf[8 * 64];   // 8 KB
    __shared__ float x2p[64 * 8];
    __shared__ __align__(16) float x2_s[64];

    const int tid = threadIdx.x;
    const int mp0 = blockIdx.x * 64;
    const int b   = blockIdx.y;
    const int lane = tid & 63, wid = tid >> 6;

    // prefetch B fragments into registers (L2-hot, coalesced 16B/lane)
    const half8* pf8 = (const half8*)pfg;
    const half8* af8 = (const half8*)afg;
    half8 bp[2][2], ba[2][2];
#pragma unroll
    for (int ot = 0; ot < 2; ++ot)
#pragma unroll
        for (int h = 0; h < 2; ++h) {
            int idx = ((wid * 2 + ot) * 2 + h) * 64 + lane;
            bp[ot][h] = pf8[idx];
            ba[ot][h] = af8[idx];
        }

    // stage x tile (f32 -> f16 fragments) + |x|^2 partials
#pragma unroll
    for (int n = 0; n < 2; ++n) {
        int s = tid + n * 256;
        int f = s >> 6, l = s & 63;
        int mt = f >> 1, h = f & 1;
        int mloc = mt * 16 + (l & 15);
        int quad = l >> 4;
        int k0 = h * 32 + quad * 8;
        int gmp = mp0 + mloc;
        int kcol = gmp & 31;
        int row  = gmp >> 5;
        half8 hv;
        float part = 0.0f;
        if (kcol < 30) {
            int gm = row * 30 + kcol;
            const float4* src = (const float4*)(x + ((size_t)gm * NB + b) * ND + k0);
            float4 v0 = src[0], v1 = src[1];
            float vv[8] = {v0.x, v0.y, v0.z, v0.w, v1.x, v1.y, v1.z, v1.w};
#pragma unroll
            for (int jj = 0; jj < 8; ++jj) {
                hv[jj] = (_Float16)vv[jj];
                part += vv[jj] * vv[jj];
            }
        } else {
#pragma unroll
            for (int jj = 0; jj < 8; ++jj) hv[jj] = (_Float16)0.0f;
        }
        xf[f * 64 + l] = hv;
        x2p[mloc * 8 + h * 4 + quad] = part;
    }
    __syncthreads();
    if (tid < 64) {
        float s = 0.0f;
#pragma unroll
        for (int r = 0; r < 8; ++r) s += x2p[tid * 8 + r];
        x2_s[tid] = s;
    }
    __syncthreads();

    // MFMA: 4 m-tiles x 2 o-tiles x {p,a} x 2 k-halves
    f32x4 accp[4][2], acca[4][2];
#pragma unroll
    for (int mt = 0; mt < 4; ++mt)
#pragma unroll
        for (int ot = 0; ot < 2; ++ot) {
            accp[mt][ot] = (f32x4)0.0f;
            acca[mt][ot] = (f32x4)0.0f;
        }
#pragma unroll
    for (int h = 0; h < 2; ++h) {
        half8 afr[4];
#pragma unroll
        for (int mt = 0; mt < 4; ++mt) afr[mt] = xf[(mt * 2 + h) * 64 + lane];
#pragma unroll
        for (int mt = 0; mt < 4; ++mt)
#pragma unroll
            for (int ot = 0; ot < 2; ++ot) {
                accp[mt][ot] = __builtin_amdgcn_mfma_f32_16x16x32_f16(
                    afr[mt], bp[ot][h], accp[mt][ot], 0, 0, 0);
                acca[mt][ot] = __builtin_amdgcn_mfma_f32_16x16x32_f16(
                    afr[mt], ba[ot][h], acca[mt][ot], 0, 0, 0);
            }
    }

    // epilogue: 4 consecutive padded-m per lane -> 8B f16 store
    const int lo = lane & 15, quad = lane >> 4;
#pragma unroll
    for (int mt = 0; mt < 4; ++mt)
#pragma unroll
        for (int ot = 0; ot < 2; ++ot) {
            int o   = wid * 32 + ot * 16 + lo;
            int mb  = mt * 16 + quad * 4;
            int gmp = mp0 + mb;
            float4 x2v = *(const float4*)&x2_s[mb];
            float P2 = p2g[o], PA = pag[o], AN = ang[o];
            half4 hv;
            hv[0] = (_Float16)gyro_dist(x2v.x, accp[mt][ot][0], acca[mt][ot][0], P2, PA, AN);
            hv[1] = (_Float16)gyro_dist(x2v.y, accp[mt][ot][1], acca[mt][ot][1], P2, PA, AN);
            hv[2] = (_Float16)gyro_dist(x2v.z, accp[mt][ot][2], acca[mt][ot][2], P2, PA, AN);
            hv[3] = (_Float16)gyro_dist(x2v.w, accp[mt][ot][3], acca[mt][ot][3], P2, PA, AN);
            *(half4*)(tmp + ((size_t)(b * NO + o)) * PML + gmp) = hv;
        }
}

// ---------------------------------------------------------------------------
// Kernel 2: 3x3x3 box sum from f16 padded tmp -> f32 output.
// Block = (slab of 8 i-planes, o, b). Single 38.4 KB LDS buffer (10 padded
// planes), in-place k/j passes with register staging (unrolled, no scratch),
// k-neighbors via shuffles. Pad cols carry d0 (right edge) / garbage that
// only ever lands in discarded .zw components of c==7 quads.
// ---------------------------------------------------------------------------
__global__ __launch_bounds__(256) void gyro_box3d_h(
    const _Float16* __restrict__ tmp, float* __restrict__ dst,
    const float* __restrict__ w, const float* __restrict__ bias) {
    __shared__ __align__(16) float vin[10 * PPLANE];   // 38.4 KB
    __shared__ float d0sh;

    const int tid = threadIdx.x;
    const int i0  = blockIdx.x * 8;
    const int o   = blockIdx.y;
    const int b   = blockIdx.z;
    const int bo  = b * NO + o;

    dist0_wave(w, bias, o, tid, &d0sh);
    __syncthreads();
    const float d0 = d0sh;
    float4* vin4 = (float4*)vin;

    // load 10 padded planes (120 x half8 each); OOB plane -> d0
    const half8* tsrc = (const half8*)(tmp + (size_t)bo * PML);
    for (int idx = tid; idx < 1200; idx += 256) {
        int sl = idx / 120, r8 = idx - sl * 120;
        int ip = i0 - 1 + sl;
        float f[8];
        if (ip >= 0 && ip < NN) {
            half8 hv = tsrc[ip * 120 + r8];
#pragma unroll
            for (int jj = 0; jj < 8; ++jj) f[jj] = (float)hv[jj];
        } else {
#pragma unroll
            for (int jj = 0; jj < 8; ++jj) f[jj] = d0;
        }
        int o4 = (sl * PPLANE + r8 * 8) >> 2;
        float4 v0; v0.x = f[0]; v0.y = f[1]; v0.z = f[2]; v0.w = f[3];
        float4 v1; v1.x = f[4]; v1.y = f[5]; v1.z = f[6]; v1.w = f[7];
        vin4[o4] = v0; vin4[o4 + 1] = v1;
    }
    __syncthreads();

    float4 st[10];

    // ---- k-pass (in-place, neighbors via shuffle; float4 index == q) ----
#pragma unroll
    for (int n = 0; n < 10; ++n) {
        int q = tid + n * 256;
        float4 cc, s;
        if (q < 2400) cc = vin4[q];
        float left  = __shfl_up(cc.w, 1);
        float right = __shfl_down(cc.x, 1);
        if (q < 2400) {
            if ((q & 7) == 0) left = d0;   // k = -1
            s.x = left + cc.x + cc.y;
            s.y = cc.x + cc.y + cc.z;
            s.z = cc.y + cc.z + cc.w;      // k=30 pad: cc.w==d0 from dist pad
            s.w = cc.z + cc.w + right;     // k=31 pad: garbage, never output
            st[n] = s;
        }
    }
    __syncthreads();
#pragma unroll
    for (int n = 0; n < 10; ++n) {
        int q = tid + n * 256;
        if (q < 2400) vin4[q] = st[n];
    }
    __syncthreads();

    // ---- j-pass (in-place) ----
    const float T3 = 3.0f * d0;
#pragma unroll
    for (int n = 0; n < 10; ++n) {
        int q = tid + n * 256;
        if (q < 2400) {
            int rem = q % 240;
            int j = rem >> 3;
            float4 cc = vin4[q];
            float4 up, dn;
            if (j == 0)  { up.x = T3; up.y = T3; up.z = T3; up.w = T3; }
            else         up = vin4[q - 8];
            if (j == 29) { dn.x = T3; dn.y = T3; dn.z = T3; dn.w = T3; }
            else         dn = vin4[q + 8];
            float4 s;
            s.x = cc.x + up.x + dn.x; s.y = cc.y + up.y + dn.y;
            s.z = cc.z + up.z + dn.z; s.w = cc.w + up.w + dn.w;
            st[n] = s;
        }
    }
    __syncthreads();
#pragma unroll
    for (int n = 0; n < 10; ++n) {
        int q = tid + n * 256;
        if (q < 2400) vin4[q] = st[n];
    }
    __syncthreads();

    // ---- i-pass + store (unpadded f32 output, 8B-aligned float2 stores) ----
    const int nout = (NN - i0 < 8) ? (NN - i0) : 8;
    for (int q = tid; q < nout * 240; q += 256) {
        int pl = q / 240, rem = q - pl * 240;
        int j = rem >> 3, c = rem & 7;
        int o4 = (pl + 1) * 240 + rem;
        float4 a = vin4[o4 - 240], m = vin4[o4], e = vin4[o4 + 240];
        float4 s;
        s.x = a.x + m.x + e.x; s.y = a.y + m.y + e.y;
        s.z = a.z + m.z + e.z; s.w = a.w + m.w + e.w;
        int i = i0 + pl;
        float* g = dst + (size_t)bo * NM + i * 900 + j * 30 + c * 4;
        float2 lo2; lo2.x = s.x; lo2.y = s.y;
        *(float2*)g = lo2;
        if (c < 7) {                      // k=28..29 only for the last quad
            float2 hi2; hi2.x = s.z; hi2.y = s.w;
            *(float2*)(g + 2) = hi2;
        }
    }
}

extern "C" void kernel_launch(void* const* d_in, const int* in_sizes, int n_in,
                              void* d_out, int out_size, void* d_ws, size_t ws_size,
                              hipStream_t stream) {
    const float* x    = (const float*)d_in[0];   // (M, B, D)
    const float* w    = (const float*)d_in[1];   // (O, D)
    const float* bias = (const float*)d_in[2];   // (O, 1)
    float* out = (float*)d_out;                  // (B, O, N, N, N)

    // ws layout: pf 32KB-half | af | p2/pa/an | f16 padded dist tmp (~112.5MB)
    // (R3 run proved ws_size >= 221 MB on this harness.)
    _Float16* pfg = (_Float16*)d_ws;                          // 8192 halves
    _Float16* afg = (_Float16*)((char*)d_ws + 16384);         // 8192 halves
    float* p2g = (float*)((char*)d_ws + 32768);
    float* pag = (float*)((char*)d_ws + 33280);
    float* ang = (float*)((char*)d_ws + 33792);
    _Float16* tmp = (_Float16*)((char*)d_ws + 36864);

    gyro_params_k<<<1, 128, 0, stream>>>(w, bias, pfg, afg, p2g, pag, ang);

    dim3 gD(PML / 64, NB);                        // (450, 16)
    gyro_dist_mfma_h<<<gD, 256, 0, stream>>>(x, pfg, afg, p2g, pag, ang, tmp);

    dim3 gB(4, NO, NB);                           // 8192 blocks
    gyro_box3d_h<<<gB, 256, 0, stream>>>(tmp, out, w, bias);
}